// Round 14
// baseline (277.570 us; speedup 1.0000x reference)
//
#include <hip/hip_runtime.h>
#include <hip/hip_bf16.h>
#include <cstdint>

#define HH 128
#define XX 128
#define RS 136  // padded LDS row stride in halfs (272 B, 16-B aligned)

typedef __attribute__((ext_vector_type(8))) short short8;
typedef __attribute__((ext_vector_type(4))) float float4_;
typedef __attribute__((ext_vector_type(8))) _Float16 half8_;
typedef __attribute__((ext_vector_type(2))) unsigned int uint2_;
typedef __attribute__((ext_vector_type(4))) unsigned int uint4_;

__device__ __forceinline__ float sigmoidf_(float x) {
  return 1.f / (1.f + __expf(-x));
}
__device__ __forceinline__ float tanhf_(float x) {
  float e = __expf(-2.f * fabsf(x));
  float t = (1.f - e) / (1.f + e);
  return copysignf(t, x);
}

// ================= combined hist + weight prep =================
// Blocks [0,1024): histogram of dst. Blocks [1024,1088): f16 weight pack.
__global__ __launch_bounds__(256) void histprep_kernel(
    const int* __restrict__ dst, int* __restrict__ cnt, int E,
    const float* __restrict__ W_iou, const float* __restrict__ U_iou,
    const float* __restrict__ b_iou, const float* __restrict__ U_f_w,
    const float* __restrict__ U_f_b, const float* __restrict__ W_f_w,
    const float* __restrict__ b_f, unsigned short* __restrict__ Bh,
    float* __restrict__ bias) {
  int b = blockIdx.x;
  if (b < 1024) {
    int e = b * 256 + threadIdx.x;
    if (e < E) atomicAdd(&cnt[dst[e]], 1);
    return;
  }
  int tid = (b - 1024) * 256 + threadIdx.x;  // 0..16383
  int kg = tid & 3;
  int c16 = (tid >> 2) & 15;
  int ks = (tid >> 6) & 7;
  int w = (tid >> 9) & 7;
  int g = (tid >> 12) & 3;
  int col = w * 16 + c16;
  int kbase = ks * 32 + kg * 8;
#pragma unroll
  for (int j = 0; j < 8; ++j) {
    int k = kbase + j;
    float v;
    if (g < 3) {
      v = (k < 128) ? W_iou[(size_t)(g * 128 + col) * 128 + k]
                    : U_iou[(size_t)(g * 128 + col) * 128 + (k - 128)];
    } else {
      v = (k < 128) ? W_f_w[(size_t)col * 128 + k]
                    : U_f_w[(size_t)col * 128 + (k - 128)];
    }
    Bh[(size_t)tid * 8 + j] = __builtin_bit_cast(unsigned short, (_Float16)v);
  }
  if (tid < 512) {
    int gg = tid >> 7, cc = tid & 127;
    bias[tid] = (gg < 3) ? b_iou[gg * 128 + cc] : (U_f_b[cc] + b_f[cc]);
  }
}

// ================= per-segment sums + top scan (last-block trick) ==========
__global__ __launch_bounds__(256) void scan_bsum_top(
    const int* __restrict__ cnt, int* __restrict__ bsum, int* __restrict__ boff,
    int* __restrict__ row_ptr, int* __restrict__ ctr, int N, int E) {
  __shared__ int red[256];
  __shared__ int amLast;
  int b = blockIdx.x, t = threadIdx.x;
  int base = b * 1024 + t * 4;
  int s = cnt[base] + cnt[base + 1] + cnt[base + 2] + cnt[base + 3];
  red[t] = s;
  __syncthreads();
  for (int off = 128; off > 0; off >>= 1) {
    if (t < off) red[t] += red[t + off];
    __syncthreads();
  }
  if (t == 0) {
    bsum[b] = red[0];
    __threadfence();
    amLast = (atomicAdd(ctr, 1) == (int)gridDim.x - 1);
  }
  __syncthreads();
  if (!amLast) return;
  __threadfence();  // acquire: all bsum writes visible
  int own = bsum[t];
  red[t] = own;
  __syncthreads();
  for (int off = 1; off < 256; off <<= 1) {
    int x = (t >= off) ? red[t - off] : 0;
    __syncthreads();
    red[t] += x;
    __syncthreads();
  }
  boff[t] = red[t] - own;  // exclusive
  if (t == 0) row_ptr[N] = E;
}

__global__ __launch_bounds__(256) void scan_fill(const int* __restrict__ cnt,
                                                 const int* __restrict__ boff,
                                                 int* __restrict__ row_ptr,
                                                 int* __restrict__ row_fill) {
  __shared__ int tsum[256];
  int b = blockIdx.x, t = threadIdx.x;
  int base = b * 1024 + t * 4;
  int v0 = cnt[base], v1 = cnt[base + 1], v2 = cnt[base + 2], v3 = cnt[base + 3];
  int s = v0 + v1 + v2 + v3;
  tsum[t] = s;
  __syncthreads();
  for (int off = 1; off < 256; off <<= 1) {
    int x = (t >= off) ? tsum[t - off] : 0;
    __syncthreads();
    tsum[t] += x;
    __syncthreads();
  }
  int excl = tsum[t] - s + boff[b];
  int p0 = excl, p1 = p0 + v0, p2 = p1 + v1, p3 = p2 + v2;
  row_ptr[base] = p0;
  row_ptr[base + 1] = p1;
  row_ptr[base + 2] = p2;
  row_ptr[base + 3] = p3;
  row_fill[base] = p0;
  row_fill[base + 1] = p1;
  row_fill[base + 2] = p2;
  row_fill[base + 3] = p3;
}

__global__ __launch_bounds__(256) void fill_kernel(const int* __restrict__ src,
                                                   const int* __restrict__ dst,
                                                   int* __restrict__ row_fill,
                                                   int* __restrict__ edge_src,
                                                   int E) {
  int e = blockIdx.x * 256 + threadIdx.x;
  if (e >= E) return;
  int pos = atomicAdd(&row_fill[dst[e]], 1);
  edge_src[pos] = src[e];
}

// ================= fused gather + MFMA GEMM + gates =================
// (identical to round-13 champion)
__device__ __forceinline__ uint4_ pack8(const float* v) {
  uint4_ r;
#pragma unroll
  for (int i = 0; i < 4; ++i)
    r[i] = __builtin_bit_cast(unsigned int,
                              __builtin_amdgcn_cvt_pkrtz(v[2 * i], v[2 * i + 1]));
  return r;
}

__device__ __forceinline__ void stage4(unsigned short* su, int baseH, int node,
                                       int k4, float4_ v) {
  uint2_ u;
  u[0] = __builtin_bit_cast(unsigned int, __builtin_amdgcn_cvt_pkrtz(v[0], v[1]));
  u[1] = __builtin_bit_cast(unsigned int, __builtin_amdgcn_cvt_pkrtz(v[2], v[3]));
  *reinterpret_cast<uint2_*>(&su[baseH + node * RS + k4]) = u;
}

__device__ __forceinline__ half8_ read_frag(const unsigned short* su, int baseH,
                                            int node, int kbase, int kq) {
  short8 s =
      *reinterpret_cast<const short8*>(&su[baseH + node * RS + kbase + kq * 8]);
  return __builtin_bit_cast(half8_, s);
}

__global__ __launch_bounds__(512, 4) void fused_mfma_kernel(
    const float* __restrict__ te, const float* __restrict__ h,
    const float* __restrict__ c, const int* __restrict__ row_ptr,
    const int* __restrict__ edge_src, const unsigned short* __restrict__ Bh,
    const float* __restrict__ bias, float* __restrict__ out_h,
    float* __restrict__ out_c) {
  __shared__ float4_ smem4[4352];  // 69632 bytes
  unsigned short* su = (unsigned short*)smem4;

  const int t = threadIdx.x;
  const int node0 = blockIdx.x * 64;

  // Phase 0: start gather dependency chain EARLY. Edge 0's rows go to regs;
  // edges 1-2 get a 1-dword warm touch so phase B hits L1/L2.
  const int nl = t >> 3;
  const int sub = t & 7;
  const int e0 = row_ptr[node0 + nl];
  const int e1 = row_ptr[node0 + nl + 1];
  int s0 = (e0 < e1) ? edge_src[e0] : 0;
  const bool has1 = (e0 + 1) < e1;
  const bool has2 = (e0 + 2) < e1;
  int s1 = edge_src[has1 ? e0 + 1 : 0];
  int s2 = edge_src[has2 ? e0 + 2 : 0];
  float4_ ph[4], pc[4];
  if (e0 < e1) {
    const float* hp = h + (size_t)s0 * HH + sub * 16;
    const float* cp = c + (size_t)s0 * HH + sub * 16;
#pragma unroll
    for (int i = 0; i < 4; ++i) {
      ph[i] = *reinterpret_cast<const float4_*>(hp + i * 4);
      pc[i] = *reinterpret_cast<const float4_*>(cp + i * 4);
    }
  }
  if (has1) {
    float w0 = h[(size_t)s1 * HH + sub * 16];
    float w1 = c[(size_t)s1 * HH + sub * 16];
    asm volatile("" ::"v"(w0), "v"(w1));  // keep the warming loads alive
  }
  if (has2) {
    float w0 = h[(size_t)s2 * HH + sub * 16];
    float w1 = c[(size_t)s2 * HH + sub * 16];
    asm volatile("" ::"v"(w0), "v"(w1));
  }

  // Phase A: stage te (nontemporal) and own-h (cached) as f16
#pragma unroll
  for (int i = 0; i < 4; ++i) {
    int q = t + i * 512;  // 0..2047 float4-chunks
    int node = q >> 5;
    int k4 = (q & 31) * 4;
    float4_ v = __builtin_nontemporal_load(
        reinterpret_cast<const float4_*>(te + (size_t)(node0 + node) * XX + k4));
    stage4(su, 0, node, k4, v);
    v = *reinterpret_cast<const float4_*>(h + (size_t)(node0 + node) * HH + k4);
    stage4(su, 17408, node, k4, v);
  }

  // Phase B: finish gather: 8 threads per node, 16 cols each.
  {
    float hs[16], cs[16];
#pragma unroll
    for (int j = 0; j < 16; ++j) {
      hs[j] = 0.f;
      cs[j] = 0.f;
    }
    if (e0 < e1) {
#pragma unroll
      for (int i = 0; i < 4; ++i)
#pragma unroll
        for (int j = 0; j < 4; ++j) {
          hs[i * 4 + j] += ph[i][j];
          cs[i * 4 + j] += pc[i][j];
        }
    }
    for (int e = e0 + 1; e < e1; ++e) {
      int s = edge_src[e];
      const float* hp = h + (size_t)s * HH + sub * 16;
      const float* cp = c + (size_t)s * HH + sub * 16;
#pragma unroll
      for (int i = 0; i < 4; ++i) {
        float4_ hv = *reinterpret_cast<const float4_*>(hp + i * 4);
        float4_ cv = *reinterpret_cast<const float4_*>(cp + i * 4);
#pragma unroll
        for (int j = 0; j < 4; ++j) {
          hs[i * 4 + j] += hv[j];
          cs[i * 4 + j] += cv[j];
        }
      }
    }
#pragma unroll
    for (int i = 0; i < 2; ++i) {
      int off = nl * RS + sub * 16 + i * 8;
      *reinterpret_cast<uint4_*>(&su[8704 + off]) = pack8(hs + i * 8);
      *reinterpret_cast<uint4_*>(&su[26112 + off]) = pack8(cs + i * 8);
    }
  }
  __syncthreads();

  const int lane = t & 63;
  const int wave = t >> 6;
  const int wc = wave * 16;  // column base (one 16-col group, all 4 gates)
  const int cl = lane & 15;
  const int kq = lane >> 4;
  const int col = wc + cl;

  // acc init = bias (MFMA C-in carries it through)
  float4_ acc[4][4];  // [gate][m]
#pragma unroll
  for (int g = 0; g < 4; ++g) {
    float b = bias[g * 128 + col];
#pragma unroll
    for (int m = 0; m < 4; ++m) acc[g][m] = (float4_){b, b, b, b};
  }

  for (int ks = 0; ks < 8; ++ks) {
    half8_ bh[4];
#pragma unroll
    for (int g = 0; g < 4; ++g) {
      size_t boff = (size_t)(((g * 8 + wave) * 8 + ks) * 512) + cl * 32 + kq * 8;
      bh[g] = __builtin_bit_cast(half8_,
                                 *reinterpret_cast<const short8*>(&Bh[boff]));
    }
    if (ks < 4) {
      int kbase = ks * 32;
#pragma unroll
      for (int m = 0; m < 4; ++m) {
        half8_ ah = read_frag(su, 0, m * 16 + cl, kbase, kq);
#pragma unroll
        for (int g = 0; g < 4; ++g)
          acc[g][m] = __builtin_amdgcn_mfma_f32_16x16x32_f16(ah, bh[g],
                                                             acc[g][m], 0, 0, 0);
      }
    } else {
      int kbase = (ks - 4) * 32;
#pragma unroll
      for (int m = 0; m < 4; ++m) {
        half8_ ah = read_frag(su, 8704, m * 16 + cl, kbase, kq);
        half8_ fh = read_frag(su, 17408, m * 16 + cl, kbase, kq);
#pragma unroll
        for (int g = 0; g < 3; ++g)
          acc[g][m] = __builtin_amdgcn_mfma_f32_16x16x32_f16(ah, bh[g],
                                                             acc[g][m], 0, 0, 0);
        acc[3][m] = __builtin_amdgcn_mfma_f32_16x16x32_f16(fh, bh[3],
                                                           acc[3][m], 0, 0, 0);
      }
    }
  }

  // Epilogue part 1: pull c_sum (f16) into regs before LDS reuse.
  float csv[4][4];
#pragma unroll
  for (int m = 0; m < 4; ++m)
#pragma unroll
    for (int r = 0; r < 4; ++r) {
      int row = m * 16 + kq * 4 + r;
      unsigned short hb = su[26112 + row * RS + col];
      csv[m][r] = (float)__builtin_bit_cast(_Float16, hb);
    }
  __syncthreads();  // all LDS reads done; safe to reuse for output assembly

  float* oh = (float*)smem4;         // words [0, 8704): h_new rows (stride RS)
  float* oc = (float*)smem4 + 8704;  // words [8704, 17408): c_new rows

  // Epilogue part 2: gates -> padded LDS assembly.
#pragma unroll
  for (int m = 0; m < 4; ++m)
#pragma unroll
    for (int r = 0; r < 4; ++r) {
      int rowl = m * 16 + kq * 4 + r;
      float ig = sigmoidf_(acc[0][m][r]);
      float og = sigmoidf_(acc[1][m][r]);
      float ug = tanhf_(acc[2][m][r]);
      float fg = sigmoidf_(acc[3][m][r]);
      float cn = fmaf(ig, ug, fg * csv[m][r]);
      int wadr = rowl * RS + col;
      oc[wadr] = cn;
      oh[wadr] = og * tanhf_(cn);
    }
  __syncthreads();

  // Stream outputs: fully coalesced float4 rows, nontemporal (never re-read).
#pragma unroll
  for (int i = 0; i < 4; ++i) {
    int q = t + i * 512;
    int rr = q >> 5;
    int k4 = (q & 31) * 4;
    int wadr = rr * RS + k4;
    __builtin_nontemporal_store(
        *reinterpret_cast<const float4_*>(&oh[wadr]),
        reinterpret_cast<float4_*>(out_h + (size_t)(node0 + rr) * HH + k4));
    __builtin_nontemporal_store(
        *reinterpret_cast<const float4_*>(&oc[wadr]),
        reinterpret_cast<float4_*>(out_c + (size_t)(node0 + rr) * HH + k4));
  }
}

extern "C" void kernel_launch(void* const* d_in, const int* in_sizes, int n_in,
                              void* d_out, int out_size, void* d_ws, size_t ws_size,
                              hipStream_t stream) {
  const float* te = (const float*)d_in[0];
  const float* h = (const float*)d_in[1];
  const float* c = (const float*)d_in[2];
  const int* src = (const int*)d_in[3];
  const int* dst = (const int*)d_in[4];
  const float* W_iou = (const float*)d_in[5];
  const float* U_iou = (const float*)d_in[6];
  const float* b_iou = (const float*)d_in[7];
  const float* U_f_w = (const float*)d_in[8];
  const float* U_f_b = (const float*)d_in[9];
  const float* W_f_w = (const float*)d_in[10];
  const float* b_f = (const float*)d_in[11];

  const int N = in_sizes[1] / HH;
  const int E = in_sizes[3];

  float* out_h = (float*)d_out;
  float* out_c = out_h + (size_t)N * HH;

  // workspace carve-up
  char* ws = (char*)d_ws;
  unsigned short* Bh = (unsigned short*)ws;              // 256 KB
  float* bias = (float*)(Bh + 4 * 8 * 8 * 16 * 4 * 8);   // 2 KB
  int* cnt = (int*)(bias + 512);                         // N ints
  int* ctr = cnt + N;                                    // 4 ints (1 used)
  int* row_ptr = ctr + 4;                                // N+4 ints
  int* row_fill = row_ptr + N + 4;                       // N ints
  int* edge_src = row_fill + N;                          // E ints
  int* bsum = edge_src + E;                              // 256
  int* boff = bsum + 256;                                // 256

  hipMemsetAsync(cnt, 0, (size_t)(N + 4) * sizeof(int), stream);

  histprep_kernel<<<1024 + 64, 256, 0, stream>>>(dst, cnt, E, W_iou, U_iou,
                                                 b_iou, U_f_w, U_f_b, W_f_w,
                                                 b_f, Bh, bias);
  scan_bsum_top<<<N / 1024, 256, 0, stream>>>(cnt, bsum, boff, row_ptr, ctr, N,
                                              E);
  scan_fill<<<N / 1024, 256, 0, stream>>>(cnt, boff, row_ptr, row_fill);
  fill_kernel<<<(E + 255) / 256, 256, 0, stream>>>(src, dst, row_fill, edge_src,
                                                   E);

  fused_mfma_kernel<<<N / 64, 512, 0, stream>>>(te, h, c, row_ptr, edge_src, Bh,
                                                bias, out_h, out_c);
}

// Round 15
// 275.158 us; speedup vs baseline: 1.0088x; 1.0088x over previous
//
#include <hip/hip_runtime.h>
#include <hip/hip_bf16.h>
#include <cstdint>

#define HH 128
#define XX 128
#define RS 136  // padded LDS row stride in halfs (272 B, 16-B aligned)

typedef __attribute__((ext_vector_type(8))) short short8;
typedef __attribute__((ext_vector_type(4))) float float4_;
typedef __attribute__((ext_vector_type(8))) _Float16 half8_;
typedef __attribute__((ext_vector_type(2))) unsigned int uint2_;
typedef __attribute__((ext_vector_type(4))) unsigned int uint4_;

__device__ __forceinline__ float sigmoidf_(float x) {
  return 1.f / (1.f + __expf(-x));
}
__device__ __forceinline__ float tanhf_(float x) {
  float e = __expf(-2.f * fabsf(x));
  float t = (1.f - e) / (1.f + e);
  return copysignf(t, x);
}

// ================= combined hist + weight prep =================
// Blocks [0,1024): histogram of dst. Blocks [1024,1088): f16 weight pack.
__global__ __launch_bounds__(256) void histprep_kernel(
    const int* __restrict__ dst, int* __restrict__ cnt, int E,
    const float* __restrict__ W_iou, const float* __restrict__ U_iou,
    const float* __restrict__ b_iou, const float* __restrict__ U_f_w,
    const float* __restrict__ U_f_b, const float* __restrict__ W_f_w,
    const float* __restrict__ b_f, unsigned short* __restrict__ Bh,
    float* __restrict__ bias) {
  int b = blockIdx.x;
  if (b < 1024) {
    int e = b * 256 + threadIdx.x;
    if (e < E) atomicAdd(&cnt[dst[e]], 1);
    return;
  }
  int tid = (b - 1024) * 256 + threadIdx.x;  // 0..16383
  int kg = tid & 3;
  int c16 = (tid >> 2) & 15;
  int ks = (tid >> 6) & 7;
  int w = (tid >> 9) & 7;
  int g = (tid >> 12) & 3;
  int col = w * 16 + c16;
  int kbase = ks * 32 + kg * 8;
#pragma unroll
  for (int j = 0; j < 8; ++j) {
    int k = kbase + j;
    float v;
    if (g < 3) {
      v = (k < 128) ? W_iou[(size_t)(g * 128 + col) * 128 + k]
                    : U_iou[(size_t)(g * 128 + col) * 128 + (k - 128)];
    } else {
      v = (k < 128) ? W_f_w[(size_t)col * 128 + k]
                    : U_f_w[(size_t)col * 128 + (k - 128)];
    }
    Bh[(size_t)tid * 8 + j] = __builtin_bit_cast(unsigned short, (_Float16)v);
  }
  if (tid < 512) {
    int gg = tid >> 7, cc = tid & 127;
    bias[tid] = (gg < 3) ? b_iou[gg * 128 + cc] : (U_f_b[cc] + b_f[cc]);
  }
}

// ================= per-segment sums + top scan (last-block trick) ==========
__global__ __launch_bounds__(256) void scan_bsum_top(
    const int* __restrict__ cnt, int* __restrict__ bsum, int* __restrict__ boff,
    int* __restrict__ row_ptr, int* __restrict__ ctr, int N, int E) {
  __shared__ int red[256];
  __shared__ int amLast;
  int b = blockIdx.x, t = threadIdx.x;
  int base = b * 1024 + t * 4;
  int s = cnt[base] + cnt[base + 1] + cnt[base + 2] + cnt[base + 3];
  red[t] = s;
  __syncthreads();
  for (int off = 128; off > 0; off >>= 1) {
    if (t < off) red[t] += red[t + off];
    __syncthreads();
  }
  if (t == 0) {
    bsum[b] = red[0];
    __threadfence();
    amLast = (atomicAdd(ctr, 1) == (int)gridDim.x - 1);
  }
  __syncthreads();
  if (!amLast) return;
  __threadfence();  // acquire: all bsum writes visible
  int own = bsum[t];
  red[t] = own;
  __syncthreads();
  for (int off = 1; off < 256; off <<= 1) {
    int x = (t >= off) ? red[t - off] : 0;
    __syncthreads();
    red[t] += x;
    __syncthreads();
  }
  boff[t] = red[t] - own;  // exclusive
  if (t == 0) row_ptr[N] = E;
}

__global__ __launch_bounds__(256) void scan_fill(const int* __restrict__ cnt,
                                                 const int* __restrict__ boff,
                                                 int* __restrict__ row_ptr,
                                                 int* __restrict__ row_fill) {
  __shared__ int tsum[256];
  int b = blockIdx.x, t = threadIdx.x;
  int base = b * 1024 + t * 4;
  int v0 = cnt[base], v1 = cnt[base + 1], v2 = cnt[base + 2], v3 = cnt[base + 3];
  int s = v0 + v1 + v2 + v3;
  tsum[t] = s;
  __syncthreads();
  for (int off = 1; off < 256; off <<= 1) {
    int x = (t >= off) ? tsum[t - off] : 0;
    __syncthreads();
    tsum[t] += x;
    __syncthreads();
  }
  int excl = tsum[t] - s + boff[b];
  int p0 = excl, p1 = p0 + v0, p2 = p1 + v1, p3 = p2 + v2;
  row_ptr[base] = p0;
  row_ptr[base + 1] = p1;
  row_ptr[base + 2] = p2;
  row_ptr[base + 3] = p3;
  row_fill[base] = p0;
  row_fill[base + 1] = p1;
  row_fill[base + 2] = p2;
  row_fill[base + 3] = p3;
}

__global__ __launch_bounds__(256) void fill_kernel(const int* __restrict__ src,
                                                   const int* __restrict__ dst,
                                                   int* __restrict__ row_fill,
                                                   int* __restrict__ edge_src,
                                                   int E) {
  int e = blockIdx.x * 256 + threadIdx.x;
  if (e >= E) return;
  int pos = atomicAdd(&row_fill[dst[e]], 1);
  edge_src[pos] = src[e];
}

// ================= fused gather + MFMA GEMM + gates =================
__device__ __forceinline__ uint4_ pack8(const float* v) {
  uint4_ r;
#pragma unroll
  for (int i = 0; i < 4; ++i)
    r[i] = __builtin_bit_cast(unsigned int,
                              __builtin_amdgcn_cvt_pkrtz(v[2 * i], v[2 * i + 1]));
  return r;
}

__device__ __forceinline__ void stage4(unsigned short* su, int baseH, int node,
                                       int k4, float4_ v) {
  uint2_ u;
  u[0] = __builtin_bit_cast(unsigned int, __builtin_amdgcn_cvt_pkrtz(v[0], v[1]));
  u[1] = __builtin_bit_cast(unsigned int, __builtin_amdgcn_cvt_pkrtz(v[2], v[3]));
  *reinterpret_cast<uint2_*>(&su[baseH + node * RS + k4]) = u;
}

__device__ __forceinline__ half8_ read_frag(const unsigned short* su, int baseH,
                                            int node, int kbase, int kq) {
  short8 s =
      *reinterpret_cast<const short8*>(&su[baseH + node * RS + kbase + kq * 8]);
  return __builtin_bit_cast(half8_, s);
}

__global__ __launch_bounds__(512, 4) void fused_mfma_kernel(
    const float* __restrict__ te, const float* __restrict__ h,
    const float* __restrict__ c, const int* __restrict__ row_ptr,
    const int* __restrict__ edge_src, const unsigned short* __restrict__ Bh,
    const float* __restrict__ bias, float* __restrict__ out_h,
    float* __restrict__ out_c) {
  __shared__ float4_ smem4[4352];  // 69632 bytes
  unsigned short* su = (unsigned short*)smem4;

  const int t = threadIdx.x;
  const int node0 = blockIdx.x * 64;

  // Phase 0: start gather dependency chain EARLY. Edge 0's rows go to regs.
  const int nl = t >> 3;
  const int sub = t & 7;
  const int e0 = row_ptr[node0 + nl];
  const int e1 = row_ptr[node0 + nl + 1];
  int s0 = (e0 < e1) ? edge_src[e0] : 0;
  float4_ ph[4], pc[4];
  if (e0 < e1) {
    const float* hp = h + (size_t)s0 * HH + sub * 16;
    const float* cp = c + (size_t)s0 * HH + sub * 16;
#pragma unroll
    for (int i = 0; i < 4; ++i) {
      ph[i] = *reinterpret_cast<const float4_*>(hp + i * 4);
      pc[i] = *reinterpret_cast<const float4_*>(cp + i * 4);
    }
  }

  // Phase A: stage te (nontemporal) and own-h (cached) as f16
#pragma unroll
  for (int i = 0; i < 4; ++i) {
    int q = t + i * 512;  // 0..2047 float4-chunks
    int node = q >> 5;
    int k4 = (q & 31) * 4;
    float4_ v = __builtin_nontemporal_load(
        reinterpret_cast<const float4_*>(te + (size_t)(node0 + node) * XX + k4));
    stage4(su, 0, node, k4, v);
    v = *reinterpret_cast<const float4_*>(h + (size_t)(node0 + node) * HH + k4);
    stage4(su, 17408, node, k4, v);
  }

  // Phase B: finish gather with a software-pipelined edge walk:
  // while accumulating edge e (rows already in ph/pc), issue edge e+1's loads.
  {
    float hs[16], cs[16];
#pragma unroll
    for (int j = 0; j < 16; ++j) {
      hs[j] = 0.f;
      cs[j] = 0.f;
    }
    for (int e = e0; e < e1; ++e) {
      const bool more = (e + 1) < e1;
      float4_ qh[4], qc[4];
      if (more) {
        int sn = edge_src[e + 1];
        const float* hp = h + (size_t)sn * HH + sub * 16;
        const float* cp = c + (size_t)sn * HH + sub * 16;
#pragma unroll
        for (int i = 0; i < 4; ++i) {
          qh[i] = *reinterpret_cast<const float4_*>(hp + i * 4);
          qc[i] = *reinterpret_cast<const float4_*>(cp + i * 4);
        }
      }
#pragma unroll
      for (int i = 0; i < 4; ++i)
#pragma unroll
        for (int j = 0; j < 4; ++j) {
          hs[i * 4 + j] += ph[i][j];
          cs[i * 4 + j] += pc[i][j];
        }
      if (more) {
#pragma unroll
        for (int i = 0; i < 4; ++i) {
          ph[i] = qh[i];
          pc[i] = qc[i];
        }
      }
    }
#pragma unroll
    for (int i = 0; i < 2; ++i) {
      int off = nl * RS + sub * 16 + i * 8;
      *reinterpret_cast<uint4_*>(&su[8704 + off]) = pack8(hs + i * 8);
      *reinterpret_cast<uint4_*>(&su[26112 + off]) = pack8(cs + i * 8);
    }
  }
  __syncthreads();

  const int lane = t & 63;
  const int wave = t >> 6;
  const int wc = wave * 16;  // column base (one 16-col group, all 4 gates)
  const int cl = lane & 15;
  const int kq = lane >> 4;
  const int col = wc + cl;

  // acc init = bias (MFMA C-in carries it through)
  float4_ acc[4][4];  // [gate][m]
#pragma unroll
  for (int g = 0; g < 4; ++g) {
    float b = bias[g * 128 + col];
#pragma unroll
    for (int m = 0; m < 4; ++m) acc[g][m] = (float4_){b, b, b, b};
  }

  for (int ks = 0; ks < 8; ++ks) {
    half8_ bh[4];
#pragma unroll
    for (int g = 0; g < 4; ++g) {
      size_t boff = (size_t)(((g * 8 + wave) * 8 + ks) * 512) + cl * 32 + kq * 8;
      bh[g] = __builtin_bit_cast(half8_,
                                 *reinterpret_cast<const short8*>(&Bh[boff]));
    }
    if (ks < 4) {
      int kbase = ks * 32;
#pragma unroll
      for (int m = 0; m < 4; ++m) {
        half8_ ah = read_frag(su, 0, m * 16 + cl, kbase, kq);
#pragma unroll
        for (int g = 0; g < 4; ++g)
          acc[g][m] = __builtin_amdgcn_mfma_f32_16x16x32_f16(ah, bh[g],
                                                             acc[g][m], 0, 0, 0);
      }
    } else {
      int kbase = (ks - 4) * 32;
#pragma unroll
      for (int m = 0; m < 4; ++m) {
        half8_ ah = read_frag(su, 8704, m * 16 + cl, kbase, kq);
        half8_ fh = read_frag(su, 17408, m * 16 + cl, kbase, kq);
#pragma unroll
        for (int g = 0; g < 3; ++g)
          acc[g][m] = __builtin_amdgcn_mfma_f32_16x16x32_f16(ah, bh[g],
                                                             acc[g][m], 0, 0, 0);
        acc[3][m] = __builtin_amdgcn_mfma_f32_16x16x32_f16(fh, bh[3],
                                                           acc[3][m], 0, 0, 0);
      }
    }
  }

  // Epilogue part 1: pull c_sum (f16) into regs before LDS reuse.
  float csv[4][4];
#pragma unroll
  for (int m = 0; m < 4; ++m)
#pragma unroll
    for (int r = 0; r < 4; ++r) {
      int row = m * 16 + kq * 4 + r;
      unsigned short hb = su[26112 + row * RS + col];
      csv[m][r] = (float)__builtin_bit_cast(_Float16, hb);
    }
  __syncthreads();  // all LDS reads done; safe to reuse for output assembly

  float* oh = (float*)smem4;         // words [0, 8704): h_new rows (stride RS)
  float* oc = (float*)smem4 + 8704;  // words [8704, 17408): c_new rows

  // Epilogue part 2: gates -> padded LDS assembly.
#pragma unroll
  for (int m = 0; m < 4; ++m)
#pragma unroll
    for (int r = 0; r < 4; ++r) {
      int rowl = m * 16 + kq * 4 + r;
      float ig = sigmoidf_(acc[0][m][r]);
      float og = sigmoidf_(acc[1][m][r]);
      float ug = tanhf_(acc[2][m][r]);
      float fg = sigmoidf_(acc[3][m][r]);
      float cn = fmaf(ig, ug, fg * csv[m][r]);
      int wadr = rowl * RS + col;
      oc[wadr] = cn;
      oh[wadr] = og * tanhf_(cn);
    }
  __syncthreads();

  // Stream outputs: fully coalesced float4 rows, nontemporal (never re-read).
#pragma unroll
  for (int i = 0; i < 4; ++i) {
    int q = t + i * 512;
    int rr = q >> 5;
    int k4 = (q & 31) * 4;
    int wadr = rr * RS + k4;
    __builtin_nontemporal_store(
        *reinterpret_cast<const float4_*>(&oh[wadr]),
        reinterpret_cast<float4_*>(out_h + (size_t)(node0 + rr) * HH + k4));
    __builtin_nontemporal_store(
        *reinterpret_cast<const float4_*>(&oc[wadr]),
        reinterpret_cast<float4_*>(out_c + (size_t)(node0 + rr) * HH + k4));
  }
}

extern "C" void kernel_launch(void* const* d_in, const int* in_sizes, int n_in,
                              void* d_out, int out_size, void* d_ws, size_t ws_size,
                              hipStream_t stream) {
  const float* te = (const float*)d_in[0];
  const float* h = (const float*)d_in[1];
  const float* c = (const float*)d_in[2];
  const int* src = (const int*)d_in[3];
  const int* dst = (const int*)d_in[4];
  const float* W_iou = (const float*)d_in[5];
  const float* U_iou = (const float*)d_in[6];
  const float* b_iou = (const float*)d_in[7];
  const float* U_f_w = (const float*)d_in[8];
  const float* U_f_b = (const float*)d_in[9];
  const float* W_f_w = (const float*)d_in[10];
  const float* b_f = (const float*)d_in[11];

  const int N = in_sizes[1] / HH;
  const int E = in_sizes[3];

  float* out_h = (float*)d_out;
  float* out_c = out_h + (size_t)N * HH;

  // workspace carve-up
  char* ws = (char*)d_ws;
  unsigned short* Bh = (unsigned short*)ws;              // 256 KB
  float* bias = (float*)(Bh + 4 * 8 * 8 * 16 * 4 * 8);   // 2 KB
  int* cnt = (int*)(bias + 512);                         // N ints
  int* ctr = cnt + N;                                    // 4 ints (1 used)
  int* row_ptr = ctr + 4;                                // N+4 ints
  int* row_fill = row_ptr + N + 4;                       // N ints
  int* edge_src = row_fill + N;                          // E ints
  int* bsum = edge_src + E;                              // 256
  int* boff = bsum + 256;                                // 256

  hipMemsetAsync(cnt, 0, (size_t)(N + 4) * sizeof(int), stream);

  histprep_kernel<<<1024 + 64, 256, 0, stream>>>(dst, cnt, E, W_iou, U_iou,
                                                 b_iou, U_f_w, U_f_b, W_f_w,
                                                 b_f, Bh, bias);
  scan_bsum_top<<<N / 1024, 256, 0, stream>>>(cnt, bsum, boff, row_ptr, ctr, N,
                                              E);
  scan_fill<<<N / 1024, 256, 0, stream>>>(cnt, boff, row_ptr, row_fill);
  fill_kernel<<<(E + 255) / 256, 256, 0, stream>>>(src, dst, row_fill, edge_src,
                                                   E);

  fused_mfma_kernel<<<N / 64, 512, 0, stream>>>(te, h, c, row_ptr, edge_src, Bh,
                                                bias, out_h, out_c);
}